// Round 3
// baseline (4999.086 us; speedup 1.0000x reference)
//
#include <hip/hip_runtime.h>
#include <math.h>

// HE color normalization: NMF (100 mult-update iters) + 0.99-quantile + recompose.
// Single persistent kernel; V and Wc live in registers for all 100 iterations.
// R2: zero-contended-RMW sync. Per-block private arrival line (plain agent-scope
// stores), master block reduces + broadcasts; workers poll one read-only flag.

#define N_PIX (1024*1024)
#define NB    256            // blocks (<= CUs, all co-resident)
#define BS    1024           // threads/block (16 waves, 4 waves/SIMD)
#define NWAVE (BS/64)
#define TT    (NB*BS)        // 262144 threads
#define PPT   (N_PIX/TT)     // 4 pixels per thread
#define NIT   100
#define EPSI  1e-8f
#define NBINS 2048

// ---- workspace layout (dword offsets) ----
#define LSTR      32                     // one 128B line per block
#define OFF_LINES 0                      // [NB][32]: floats 0..21 partials / [0] max; u32 [31] epoch
#define OFF_BCAST (NB*LSTR)              // 32 dwords: floats 0..27 data; u32 [31] gflag; u32 [1],[2] ints
#define OFF_GH0   (OFF_BCAST + 32)
#define OFF_GH1   (OFF_GH0 + NBINS)
#define WS_DWORDS (OFF_GH1 + NBINS)
#define WS_BYTES  (WS_DWORDS*4)

__device__ __forceinline__ unsigned ld_acq_u(const unsigned* p) {
    return __hip_atomic_load(p, __ATOMIC_ACQUIRE, __HIP_MEMORY_SCOPE_AGENT);
}
__device__ __forceinline__ unsigned ld_rlx_u(const unsigned* p) {
    return __hip_atomic_load(p, __ATOMIC_RELAXED, __HIP_MEMORY_SCOPE_AGENT);
}
__device__ __forceinline__ float ld_rlx_f(const float* p) {
    return __hip_atomic_load(p, __ATOMIC_RELAXED, __HIP_MEMORY_SCOPE_AGENT);
}
__device__ __forceinline__ void st_rlx_f(float* p, float v) {
    __hip_atomic_store(p, v, __ATOMIC_RELAXED, __HIP_MEMORY_SCOPE_AGENT);
}
__device__ __forceinline__ void st_rel_u(unsigned* p, unsigned v) {
    __hip_atomic_store(p, v, __ATOMIC_RELEASE, __HIP_MEMORY_SCOPE_AGENT);
}

__global__ __launch_bounds__(BS)
void he_norm_kernel(const float* __restrict__ pic,      // (3,N)
                    const float* __restrict__ Wt,       // (3,4)
                    const float* __restrict__ HtRM,     // scalar
                    const float* __restrict__ W0,       // (N,4)
                    const float* __restrict__ H0,       // (3,4)
                    float* __restrict__ out,            // (3,N)
                    unsigned char* __restrict__ ws)
{
    const int tid  = threadIdx.x;
    const int blk  = blockIdx.x;
    const int g    = blk*BS + tid;
    const int wave = tid >> 6;
    const int lane = tid & 63;

    unsigned* U = (unsigned*)ws;
    float*    F = (float*)ws;
    unsigned* gflag = U + OFF_BCAST + 31;
    float*    BCF   = F + OFF_BCAST;
    unsigned* BCU   = U + OFF_BCAST;
    unsigned* gh0   = U + OFF_GH0;
    unsigned* gh1   = U + OFF_GH1;

    __shared__ float sHd[12], sG[16], sHdN[12], sGN[16], sS[22], sWt[12], sScal[2];
    __shared__ float sRed[NWAVE][24];
    __shared__ float sPr[16][22];
    __shared__ unsigned sHist[NBINS];
    __shared__ unsigned sSeg[256];
    __shared__ int      sBstar;
    __shared__ unsigned sCumB;

    // ---- setup: Hd = H0, Wt to LDS ----
    if (tid < 12) { sHd[tid] = H0[tid]; sWt[tid] = Wt[tid]; }
    __syncthreads();
    if (tid < 16) {
        int s_ = tid >> 2, r_ = tid & 3;
        sG[tid] = sHd[s_]*sHd[r_] + sHd[4+s_]*sHd[4+r_] + sHd[8+s_]*sHd[8+r_];
    }

    // ---- persistent registers: V (optical density) and Wc ----
    float v0[PPT], v1[PPT], v2[PPT];
    float w[PPT][4];
    #pragma unroll
    for (int k = 0; k < PPT; k++) {
        int i = g + k*TT;
        float4 wv = ((const float4*)W0)[i];
        w[k][0]=wv.x; w[k][1]=wv.y; w[k][2]=wv.z; w[k][3]=wv.w;
        v0[k] = -logf(fminf(fmaxf(pic[i],           0.01f), 0.99f));
        v1[k] = -logf(fminf(fmaxf(pic[N_PIX  + i],  0.01f), 0.99f));
        v2[k] = -logf(fminf(fmaxf(pic[2*N_PIX + i], 0.01f), 0.99f));
    }
    __syncthreads();   // sG ready

    // ---- NMF multiplicative updates ----
    for (int t = 0; t < NIT; ++t) {
        float hd[12], gg[16];
        #pragma unroll
        for (int j = 0; j < 12; j++) hd[j] = sHd[j];
        #pragma unroll
        for (int j = 0; j < 16; j++) gg[j] = sG[j];

        float acc[22];
        #pragma unroll
        for (int j = 0; j < 22; j++) acc[j] = 0.f;

        #pragma unroll
        for (int k = 0; k < PPT; k++) {
            float wn[4];
            #pragma unroll
            for (int r = 0; r < 4; r++) {
                float num = v0[k]*hd[r] + v1[k]*hd[4+r] + v2[k]*hd[8+r];
                float den = w[k][0]*gg[r] + w[k][1]*gg[4+r]
                          + w[k][2]*gg[8+r] + w[k][3]*gg[12+r] + EPSI;
                float rc = __builtin_amdgcn_rcpf(den);
                rc = rc * (2.0f - den*rc);          // 1 NR step: ~exact
                wn[r] = w[k][r] * num * rc;
            }
            #pragma unroll
            for (int r = 0; r < 4; r++) {
                acc[r]    += v0[k]*wn[r];
                acc[4+r]  += v1[k]*wn[r];
                acc[8+r]  += v2[k]*wn[r];
            }
            acc[12]+=wn[0]*wn[0]; acc[13]+=wn[0]*wn[1]; acc[14]+=wn[0]*wn[2]; acc[15]+=wn[0]*wn[3];
            acc[16]+=wn[1]*wn[1]; acc[17]+=wn[1]*wn[2]; acc[18]+=wn[1]*wn[3];
            acc[19]+=wn[2]*wn[2]; acc[20]+=wn[2]*wn[3]; acc[21]+=wn[3]*wn[3];
            w[k][0]=wn[0]; w[k][1]=wn[1]; w[k][2]=wn[2]; w[k][3]=wn[3];
        }

        if (t == NIT-1) break;   // last Hd update is dead code (output uses Wc only)
        const unsigned ep = (unsigned)(t + 1);

        // ---- block reduce 22 accumulators ----
        #pragma unroll
        for (int j = 0; j < 22; j++) {
            float v = acc[j];
            #pragma unroll
            for (int off = 32; off > 0; off >>= 1) v += __shfl_down(v, off, 64);
            if (lane == 0) sRed[wave][j] = v;
        }
        __syncthreads();
        if (tid < 22) {
            float pa = 0.f;
            #pragma unroll
            for (int wv2 = 0; wv2 < NWAVE; wv2++) pa += sRed[wv2][tid];
            st_rlx_f(&F[blk*LSTR + tid], pa);       // private line, no contention
        }
        __syncthreads();                            // drain stores
        if (tid == 0) { __threadfence(); st_rel_u(&U[blk*LSTR + 31], ep); }

        if (blk == 0) {
            // master: parallel wait-all (one thread per line)
            if (tid < NB) {
                const unsigned* p = &U[tid*LSTR + 31];
                while (ld_acq_u(p) < ep) __builtin_amdgcn_s_sleep(1);
            }
            __syncthreads();
            // fixed-order reduction: 16 segs x 22 accs, 16 blocks each
            if (tid < 352) {
                int seg = tid / 22, j = tid - seg*22;
                float s = 0.f;
                #pragma unroll
                for (int b2 = 0; b2 < 16; b2++)
                    s += ld_rlx_f(&F[(seg*16 + b2)*LSTR + j]);
                sPr[seg][j] = s;
            }
            __syncthreads();
            if (tid < 22) {
                float s = 0.f;
                #pragma unroll
                for (int sg = 0; sg < 16; sg++) s += sPr[sg][tid];
                sS[tid] = s;
            }
            __syncthreads();
            if (tid < 12) {                        // Hd update
                int c = tid >> 2, r = tid & 3;
                const int base[4] = {12, 16, 19, 21};
                float den = EPSI;
                #pragma unroll
                for (int s2 = 0; s2 < 4; s2++) {
                    int lo = min(s2, r), hi = max(s2, r);
                    den += sHd[c*4 + s2] * sS[base[lo] + (hi - lo)];
                }
                sHdN[tid] = sHd[tid] * sS[tid] / den;
            }
            __syncthreads();
            if (tid < 16) {                        // new Gram
                int s_ = tid >> 2, r_ = tid & 3;
                sGN[tid] = sHdN[s_]*sHdN[r_] + sHdN[4+s_]*sHdN[4+r_] + sHdN[8+s_]*sHdN[8+r_];
            }
            __syncthreads();
            if (tid < 12) st_rlx_f(&BCF[tid], sHdN[tid]);
            if (tid >= 12 && tid < 28) st_rlx_f(&BCF[tid], sGN[tid - 12]);
            __syncthreads();                       // drain bcast stores
            if (tid == 0) { __threadfence(); st_rel_u(gflag, ep); }
        }

        // all blocks: wait broadcast, pull new Hd/G
        if (tid == 0) {
            while (ld_acq_u(gflag) < ep) __builtin_amdgcn_s_sleep(1);
        }
        __syncthreads();
        if (tid < 12) sHd[tid] = ld_rlx_f(&BCF[tid]);
        if (tid >= 12 && tid < 28) sG[tid - 12] = ld_rlx_f(&BCF[tid]);
        __syncthreads();
    }

    // ================= tail: quantile + recompose =================
    // ---- phase 100: global max of Wc ----
    float m = 0.f;
    #pragma unroll
    for (int k = 0; k < PPT; k++)
        #pragma unroll
        for (int r = 0; r < 4; r++) m = fmaxf(m, w[k][r]);
    #pragma unroll
    for (int off = 32; off > 0; off >>= 1) m = fmaxf(m, __shfl_down(m, off, 64));
    if (lane == 0) sRed[wave][0] = m;
    __syncthreads();
    if (tid == 0) {
        float mm = 0.f;
        for (int wv2 = 0; wv2 < NWAVE; wv2++) mm = fmaxf(mm, sRed[wv2][0]);
        st_rlx_f(&F[blk*LSTR], mm);
        __threadfence();
        st_rel_u(&U[blk*LSTR + 31], 100u);
    }
    if (blk == 0) {
        if (tid < NB) {
            const unsigned* p = &U[tid*LSTR + 31];
            while (ld_acq_u(p) < 100u) __builtin_amdgcn_s_sleep(1);
        }
        __syncthreads();
        if (tid < NB) {
            float mv = ld_rlx_f(&F[tid*LSTR]);
            #pragma unroll
            for (int off = 32; off > 0; off >>= 1) mv = fmaxf(mv, __shfl_down(mv, off, 64));
            if (lane == 0) sRed[wave][1] = mv;
        }
        __syncthreads();
        if (tid == 0) {
            float mm = 0.f;
            for (int wv2 = 0; wv2 < 4; wv2++) mm = fmaxf(mm, sRed[wv2][1]);
            st_rlx_f(&BCF[0], mm * 1.0000002f);
            __threadfence();
            st_rel_u(gflag, 100u);
        }
    }
    if (tid == 0) {
        while (ld_acq_u(gflag) < 100u) __builtin_amdgcn_s_sleep(1);
        sScal[0] = ld_rlx_f(&BCF[0]);
    }
    __syncthreads();
    const float gmax   = sScal[0];
    const float scale0 = (float)NBINS / gmax;

    // ---- phase 101: histogram level 0 ----
    for (int i = tid; i < NBINS; i += BS) sHist[i] = 0u;
    __syncthreads();
    #pragma unroll
    for (int k = 0; k < PPT; k++)
        #pragma unroll
        for (int r = 0; r < 4; r++) {
            int b = (int)(w[k][r] * scale0);
            b = min(b, NBINS - 1);
            atomicAdd(&sHist[b], 1u);
        }
    __syncthreads();
    for (int i = tid; i < NBINS; i += BS) if (sHist[i]) atomicAdd(&gh0[i], sHist[i]);
    __syncthreads();
    if (tid == 0) { __threadfence(); st_rel_u(&U[blk*LSTR + 31], 101u); }

    const double kfd = 0.99 * (double)(4*N_PIX - 1);   // fractional rank
    if (blk == 0) {
        if (tid < NB) {
            const unsigned* p = &U[tid*LSTR + 31];
            while (ld_acq_u(p) < 101u) __builtin_amdgcn_s_sleep(1);
        }
        __syncthreads();
        if (tid < 256) {
            unsigned s2 = 0;
            for (int i = 0; i < 8; i++) s2 += ld_rlx_u(&gh0[tid*8 + i]);
            sSeg[tid] = s2;
        }
        __syncthreads();
        if (tid == 0) {
            unsigned cum = 0; int seg = 0;
            for (int i2 = 0; i2 < 256; i2++) {
                if ((double)(cum + sSeg[i2]) > kfd) { seg = i2; break; }
                cum += sSeg[i2];
            }
            unsigned c2 = cum; int b = seg*8;
            for (int i2 = 0; i2 < 8; i2++) {
                unsigned h = ld_rlx_u(&gh0[seg*8 + i2]);
                if ((double)(c2 + h) > kfd) { b = seg*8 + i2; break; }
                c2 += h;
            }
            sCumB = c2;
            BCU[1] = (unsigned)b;                 // relaxed store via plain? keep atomic:
            st_rel_u(&BCU[1], (unsigned)b);
            __threadfence();
            st_rel_u(gflag, 101u);
        }
    }
    if (tid == 0) {
        while (ld_acq_u(gflag) < 101u) __builtin_amdgcn_s_sleep(1);
        sBstar = (int)ld_rlx_u(&BCU[1]);
    }
    __syncthreads();
    const int   bstar  = sBstar;
    const float lo1    = (float)bstar / scale0;
    const float scale1 = scale0 * (float)NBINS;

    // ---- phase 102: histogram level 1 (values inside bin bstar only) ----
    for (int i = tid; i < NBINS; i += BS) sHist[i] = 0u;
    __syncthreads();
    #pragma unroll
    for (int k = 0; k < PPT; k++)
        #pragma unroll
        for (int r = 0; r < 4; r++) {
            int b0 = min((int)(w[k][r] * scale0), NBINS - 1);
            if (b0 == bstar) {
                int b1 = (int)((w[k][r] - lo1) * scale1);
                b1 = max(0, min(b1, NBINS - 1));
                atomicAdd(&sHist[b1], 1u);
            }
        }
    __syncthreads();
    for (int i = tid; i < NBINS; i += BS) if (sHist[i]) atomicAdd(&gh1[i], sHist[i]);
    __syncthreads();
    if (tid == 0) { __threadfence(); st_rel_u(&U[blk*LSTR + 31], 102u); }

    if (blk == 0) {
        if (tid < NB) {
            const unsigned* p = &U[tid*LSTR + 31];
            while (ld_acq_u(p) < 102u) __builtin_amdgcn_s_sleep(1);
        }
        __syncthreads();
        if (tid < 256) {
            unsigned s2 = 0;
            for (int i = 0; i < 8; i++) s2 += ld_rlx_u(&gh1[tid*8 + i]);
            sSeg[tid] = s2;
        }
        __syncthreads();
        if (tid == 0) {
            double jf = kfd - (double)sCumB;
            unsigned cum = 0; int seg = 0;
            for (int i2 = 0; i2 < 256; i2++) {
                if ((double)(cum + sSeg[i2]) > jf) { seg = i2; break; }
                cum += sSeg[i2];
            }
            unsigned c3 = cum; int bb = seg*8; unsigned hh = 1;
            for (int i2 = 0; i2 < 8; i2++) {
                unsigned h = ld_rlx_u(&gh1[seg*8 + i2]);
                if ((double)(c3 + h) > jf) { bb = seg*8 + i2; hh = h; break; }
                c3 += h;
            }
            double frac = (jf - (double)c3 + 0.5) / (double)hh;
            frac = fmin(fmax(frac, 0.0), 1.0);
            double q = (double)lo1 + ((double)bb + frac) / (double)scale1;
            st_rlx_f(&BCF[0], (float)((double)HtRM[0] / q));
            __threadfence();
            st_rel_u(gflag, 102u);
        }
    }
    if (tid == 0) {
        while (ld_acq_u(gflag) < 102u) __builtin_amdgcn_s_sleep(1);
        sScal[1] = ld_rlx_f(&BCF[0]);
    }
    __syncthreads();
    const float sc = sScal[1];

    // ---- recompose: out = clip(exp(-(Wt @ (Wc^T * sc))), 0, 1) ----
    #pragma unroll
    for (int k = 0; k < PPT; k++) {
        int i = g + k*TT;
        #pragma unroll
        for (int c = 0; c < 3; c++) {
            float d = sWt[c*4+0]*w[k][0] + sWt[c*4+1]*w[k][1]
                    + sWt[c*4+2]*w[k][2] + sWt[c*4+3]*w[k][3];
            float e = expf(-d * sc);
            out[c*N_PIX + i] = fminf(fmaxf(e, 0.f), 1.f);
        }
    }
}

extern "C" void kernel_launch(void* const* d_in, const int* in_sizes, int n_in,
                              void* d_out, int out_size, void* d_ws, size_t ws_size,
                              hipStream_t stream) {
    const float* pic  = (const float*)d_in[0];
    const float* Wt   = (const float*)d_in[1];
    const float* HtRM = (const float*)d_in[2];
    const float* W0   = (const float*)d_in[3];
    const float* H0   = (const float*)d_in[4];
    float* out = (float*)d_out;

    // zero arrival lines, broadcast slot, histograms
    hipMemsetAsync(d_ws, 0, WS_BYTES, stream);
    he_norm_kernel<<<dim3(NB), dim3(BS), 0, stream>>>(
        pic, Wt, HtRM, W0, H0, out, (unsigned char*)d_ws);
}

// Round 4
// 1166.987 us; speedup vs baseline: 4.2838x; 4.2838x over previous
//
#include <hip/hip_runtime.h>
#include <math.h>

// HE color normalization: NMF (100 mult-update iters) + 0.99-quantile + recompose.
// Single persistent kernel; V and Wc live in registers for all 100 iterations.
// R3: fence-free RMW-free symmetric exchange. Each block owns a private
// parity-double-buffered 128B line (22 float partials + epoch word), written with
// RELAXED agent atomics + explicit s_waitcnt ordering. All blocks poll all 256
// epoch words in parallel (relaxed loads, distinct lines) and redundantly reduce
// the payloads in fixed order. No atomic RMW, no fences, no acquire/release ops
// anywhere in the iteration path.

#define N_PIX (1024*1024)
#define NB    256            // blocks (1 per CU, co-resident)
#define BS    512            // threads/block (8 waves)
#define NWAVE (BS/64)
#define TT    (NB*BS)
#define PPT   (N_PIX/TT)     // 8 pixels per thread
#define NIT   100
#define EPSI  1e-8f
#define NBINS 2048
#define LSTR  32             // dwords per line (128B)

// ---- workspace layout (dword offsets) ----
#define OFF_LINES 0                    // [NB][2][LSTR]: floats 0..21 payload, u32 [31] epoch
#define OFF_GH0   (NB*2*LSTR)
#define OFF_GH1   (OFF_GH0 + NBINS)
#define WS_DWORDS (OFF_GH1 + NBINS)
#define WS_BYTES  (WS_DWORDS*4)

__device__ __forceinline__ unsigned ld_rlx_u(const unsigned* p) {
    return __hip_atomic_load(p, __ATOMIC_RELAXED, __HIP_MEMORY_SCOPE_AGENT);
}
__device__ __forceinline__ float ld_rlx_f(const float* p) {
    return __hip_atomic_load(p, __ATOMIC_RELAXED, __HIP_MEMORY_SCOPE_AGENT);
}
__device__ __forceinline__ void st_rlx_f(float* p, float v) {
    __hip_atomic_store(p, v, __ATOMIC_RELAXED, __HIP_MEMORY_SCOPE_AGENT);
}
__device__ __forceinline__ void st_rlx_u(unsigned* p, unsigned v) {
    __hip_atomic_store(p, v, __ATOMIC_RELAXED, __HIP_MEMORY_SCOPE_AGENT);
}

__global__ __launch_bounds__(BS)
void he_norm_kernel(const float* __restrict__ pic,      // (3,N)
                    const float* __restrict__ Wt,       // (3,4)
                    const float* __restrict__ HtRM,     // scalar
                    const float* __restrict__ W0,       // (N,4)
                    const float* __restrict__ H0,       // (3,4)
                    float* __restrict__ out,            // (3,N)
                    unsigned char* __restrict__ ws)
{
    const int tid  = threadIdx.x;
    const int blk  = blockIdx.x;
    const int g    = blk*BS + tid;
    const int wave = tid >> 6;
    const int lane = tid & 63;

    unsigned* U = (unsigned*)ws;
    float*    F = (float*)ws;
    unsigned* gh0 = U + OFF_GH0;
    unsigned* gh1 = U + OFF_GH1;

    __shared__ float sHd[12], sG[16], sS[22], sWt[12], sScal[2];
    __shared__ float sRed[NWAVE][24];
    __shared__ float sPr[16][22];
    __shared__ unsigned sHist[NBINS];
    __shared__ unsigned sSeg[256];
    __shared__ int      sBstar;
    __shared__ unsigned sCumB;

    // ---- setup ----
    if (tid < 12) { sHd[tid] = H0[tid]; sWt[tid] = Wt[tid]; }
    __syncthreads();
    if (tid < 16) {
        int s_ = tid >> 2, r_ = tid & 3;
        sG[tid] = sHd[s_]*sHd[r_] + sHd[4+s_]*sHd[4+r_] + sHd[8+s_]*sHd[8+r_];
    }

    // ---- persistent registers: V (optical density) and Wc ----
    float v0[PPT], v1[PPT], v2[PPT];
    float w[PPT][4];
    #pragma unroll
    for (int k = 0; k < PPT; k++) {
        int i = g + k*TT;
        float4 wv = ((const float4*)W0)[i];
        w[k][0]=wv.x; w[k][1]=wv.y; w[k][2]=wv.z; w[k][3]=wv.w;
        v0[k] = -logf(fminf(fmaxf(pic[i],           0.01f), 0.99f));
        v1[k] = -logf(fminf(fmaxf(pic[N_PIX  + i],  0.01f), 0.99f));
        v2[k] = -logf(fminf(fmaxf(pic[2*N_PIX + i], 0.01f), 0.99f));
    }
    __syncthreads();   // sG ready

    // ---- NMF multiplicative updates ----
    for (int t = 0; t < NIT; ++t) {
        float hd[12], gg[16];
        #pragma unroll
        for (int j = 0; j < 12; j++) hd[j] = sHd[j];
        #pragma unroll
        for (int j = 0; j < 16; j++) gg[j] = sG[j];

        float acc[22];
        #pragma unroll
        for (int j = 0; j < 22; j++) acc[j] = 0.f;

        #pragma unroll
        for (int k = 0; k < PPT; k++) {
            float wn[4];
            #pragma unroll
            for (int r = 0; r < 4; r++) {
                float num = v0[k]*hd[r] + v1[k]*hd[4+r] + v2[k]*hd[8+r];
                float den = w[k][0]*gg[r] + w[k][1]*gg[4+r]
                          + w[k][2]*gg[8+r] + w[k][3]*gg[12+r] + EPSI;
                float rc = __builtin_amdgcn_rcpf(den);
                rc = rc * (2.0f - den*rc);          // 1 NR step: ~exact
                wn[r] = w[k][r] * num * rc;
            }
            #pragma unroll
            for (int r = 0; r < 4; r++) {
                acc[r]    += v0[k]*wn[r];
                acc[4+r]  += v1[k]*wn[r];
                acc[8+r]  += v2[k]*wn[r];
            }
            acc[12]+=wn[0]*wn[0]; acc[13]+=wn[0]*wn[1]; acc[14]+=wn[0]*wn[2]; acc[15]+=wn[0]*wn[3];
            acc[16]+=wn[1]*wn[1]; acc[17]+=wn[1]*wn[2]; acc[18]+=wn[1]*wn[3];
            acc[19]+=wn[2]*wn[2]; acc[20]+=wn[2]*wn[3]; acc[21]+=wn[3]*wn[3];
            w[k][0]=wn[0]; w[k][1]=wn[1]; w[k][2]=wn[2]; w[k][3]=wn[3];
        }

        if (t == NIT-1) break;   // last Hd update is dead code (output uses Wc only)
        const unsigned ep  = (unsigned)(t + 1);
        const int      par = (int)(ep & 1u);

        // ---- block reduce 22 accumulators ----
        #pragma unroll
        for (int j = 0; j < 22; j++) {
            float v = acc[j];
            #pragma unroll
            for (int off = 32; off > 0; off >>= 1) v += __shfl_down(v, off, 64);
            if (lane == 0) sRed[wave][j] = v;
        }
        __syncthreads();

        // ---- publish: payload then flag, ordered by in-wave s_waitcnt ----
        if (wave == 0) {
            if (tid < 22) {
                float pa = 0.f;
                #pragma unroll
                for (int wv2 = 0; wv2 < NWAVE; wv2++) pa += sRed[wv2][tid];
                st_rlx_f(&F[(blk*2 + par)*LSTR + tid], pa);
            }
            __builtin_amdgcn_s_waitcnt(0);          // payload acked at coherence point
            if (tid == 0) st_rlx_u(&U[(blk*2 + par)*LSTR + 31], ep);
        }

        // ---- parallel poll of all 256 epoch words (relaxed, distinct lines) ----
        if (tid < NB) {
            const unsigned* p = &U[(tid*2 + par)*LSTR + 31];
            while (ld_rlx_u(p) < ep) __builtin_amdgcn_s_sleep(1);
        }
        __syncthreads();

        // ---- fixed-order redundant reduction: 16 segs x 22 accs ----
        if (tid < 352) {
            int seg = tid / 22, j = tid - seg*22;
            float s = 0.f;
            #pragma unroll
            for (int b2 = 0; b2 < 16; b2++)
                s += ld_rlx_f(&F[((seg*16 + b2)*2 + par)*LSTR + j]);
            sPr[seg][j] = s;
        }
        __syncthreads();
        if (tid < 22) {
            float s = 0.f;
            #pragma unroll
            for (int sg = 0; sg < 16; sg++) s += sPr[sg][tid];
            sS[tid] = s;
        }
        __syncthreads();

        // ---- Hd + Gram update (redundant, identical in every block) ----
        if (tid < 12) {
            int c = tid >> 2, r = tid & 3;
            const int base[4] = {12, 16, 19, 21};
            float den = EPSI;
            #pragma unroll
            for (int s2 = 0; s2 < 4; s2++) {
                int lo = min(s2, r), hi = max(s2, r);
                den += sHd[c*4 + s2] * sS[base[lo] + (hi - lo)];
            }
            sRed[0][tid] = sHd[tid] * sS[tid] / den;   // staging for new Hd
        }
        __syncthreads();
        if (tid < 12) sHd[tid] = sRed[0][tid];
        __syncthreads();
        if (tid < 16) {
            int s_ = tid >> 2, r_ = tid & 3;
            sG[tid] = sHd[s_]*sHd[r_] + sHd[4+s_]*sHd[4+r_] + sHd[8+s_]*sHd[8+r_];
        }
        __syncthreads();
    }

    // ================= tail: quantile + recompose =================
    // ---- ep=100: global max of Wc ----
    {
        float m = 0.f;
        #pragma unroll
        for (int k = 0; k < PPT; k++)
            #pragma unroll
            for (int r = 0; r < 4; r++) m = fmaxf(m, w[k][r]);
        #pragma unroll
        for (int off = 32; off > 0; off >>= 1) m = fmaxf(m, __shfl_down(m, off, 64));
        if (lane == 0) sRed[wave][0] = m;
        __syncthreads();
        const unsigned ep = 100u; const int par = 0;
        if (tid == 0) {
            float mm = 0.f;
            for (int wv2 = 0; wv2 < NWAVE; wv2++) mm = fmaxf(mm, sRed[wv2][0]);
            st_rlx_f(&F[(blk*2 + par)*LSTR], mm);
            __builtin_amdgcn_s_waitcnt(0);
            st_rlx_u(&U[(blk*2 + par)*LSTR + 31], ep);
        }
        if (tid < NB) {
            const unsigned* p = &U[(tid*2 + par)*LSTR + 31];
            while (ld_rlx_u(p) < ep) __builtin_amdgcn_s_sleep(1);
        }
        __syncthreads();
        if (tid < NB) {
            float mv = ld_rlx_f(&F[(tid*2 + par)*LSTR]);
            #pragma unroll
            for (int off = 32; off > 0; off >>= 1) mv = fmaxf(mv, __shfl_down(mv, off, 64));
            if (lane == 0) sRed[wave][1] = mv;
        }
        __syncthreads();
        if (tid == 0) {
            float mm = 0.f;
            for (int wv2 = 0; wv2 < 4; wv2++) mm = fmaxf(mm, sRed[wv2][1]);
            sScal[0] = mm * 1.0000002f;
        }
        __syncthreads();
    }
    const float gmax   = sScal[0];
    const float scale0 = (float)NBINS / gmax;

    // ---- ep=101: histogram level 0 ----
    for (int i = tid; i < NBINS; i += BS) sHist[i] = 0u;
    __syncthreads();
    #pragma unroll
    for (int k = 0; k < PPT; k++)
        #pragma unroll
        for (int r = 0; r < 4; r++) {
            int b = (int)(w[k][r] * scale0);
            b = min(b, NBINS - 1);
            atomicAdd(&sHist[b], 1u);
        }
    __syncthreads();
    for (int i = tid; i < NBINS; i += BS) if (sHist[i]) atomicAdd(&gh0[i], sHist[i]);
    __builtin_amdgcn_s_waitcnt(0);      // every wave: its hist atomics acked
    __syncthreads();
    if (tid == 0) st_rlx_u(&U[(blk*2 + 1)*LSTR + 31], 101u);
    if (tid < NB) {
        const unsigned* p = &U[(tid*2 + 1)*LSTR + 31];
        while (ld_rlx_u(p) < 101u) __builtin_amdgcn_s_sleep(1);
    }
    __syncthreads();

    // ---- scan level 0 (redundant in every block, exact integer counts) ----
    const double kfd = 0.99 * (double)(4*N_PIX - 1);   // fractional rank
    if (tid < 256) {
        unsigned s2 = 0;
        for (int i = 0; i < 8; i++) s2 += ld_rlx_u(&gh0[tid*8 + i]);
        sSeg[tid] = s2;
    }
    __syncthreads();
    if (tid == 0) {
        unsigned cum = 0; int seg = 0;
        for (int i2 = 0; i2 < 256; i2++) {
            if ((double)(cum + sSeg[i2]) > kfd) { seg = i2; break; }
            cum += sSeg[i2];
        }
        unsigned c2 = cum; int b = seg*8;
        for (int i2 = 0; i2 < 8; i2++) {
            unsigned h = ld_rlx_u(&gh0[seg*8 + i2]);
            if ((double)(c2 + h) > kfd) { b = seg*8 + i2; break; }
            c2 += h;
        }
        sBstar = b; sCumB = c2;
    }
    __syncthreads();
    const int   bstar  = sBstar;
    const float lo1    = (float)bstar / scale0;
    const float scale1 = scale0 * (float)NBINS;

    // ---- ep=102: histogram level 1 (values inside bin bstar only) ----
    for (int i = tid; i < NBINS; i += BS) sHist[i] = 0u;
    __syncthreads();
    #pragma unroll
    for (int k = 0; k < PPT; k++)
        #pragma unroll
        for (int r = 0; r < 4; r++) {
            int b0 = min((int)(w[k][r] * scale0), NBINS - 1);
            if (b0 == bstar) {
                int b1 = (int)((w[k][r] - lo1) * scale1);
                b1 = max(0, min(b1, NBINS - 1));
                atomicAdd(&sHist[b1], 1u);
            }
        }
    __syncthreads();
    for (int i = tid; i < NBINS; i += BS) if (sHist[i]) atomicAdd(&gh1[i], sHist[i]);
    __builtin_amdgcn_s_waitcnt(0);
    __syncthreads();
    if (tid == 0) st_rlx_u(&U[(blk*2 + 0)*LSTR + 31], 102u);
    if (tid < NB) {
        const unsigned* p = &U[(tid*2 + 0)*LSTR + 31];
        while (ld_rlx_u(p) < 102u) __builtin_amdgcn_s_sleep(1);
    }
    __syncthreads();

    // ---- scan level 1 -> quantile -> scale factor (redundant) ----
    if (tid < 256) {
        unsigned s2 = 0;
        for (int i = 0; i < 8; i++) s2 += ld_rlx_u(&gh1[tid*8 + i]);
        sSeg[tid] = s2;
    }
    __syncthreads();
    if (tid == 0) {
        double jf = kfd - (double)sCumB;
        unsigned cum = 0; int seg = 0;
        for (int i2 = 0; i2 < 256; i2++) {
            if ((double)(cum + sSeg[i2]) > jf) { seg = i2; break; }
            cum += sSeg[i2];
        }
        unsigned c3 = cum; int bb = seg*8; unsigned hh = 1;
        for (int i2 = 0; i2 < 8; i2++) {
            unsigned h = ld_rlx_u(&gh1[seg*8 + i2]);
            if ((double)(c3 + h) > jf) { bb = seg*8 + i2; hh = h; break; }
            c3 += h;
        }
        double frac = (jf - (double)c3 + 0.5) / (double)hh;
        frac = fmin(fmax(frac, 0.0), 1.0);
        double q = (double)lo1 + ((double)bb + frac) / (double)scale1;
        sScal[1] = (float)((double)HtRM[0] / q);
    }
    __syncthreads();
    const float sc = sScal[1];

    // ---- recompose: out = clip(exp(-(Wt @ (Wc^T * sc))), 0, 1) ----
    #pragma unroll
    for (int k = 0; k < PPT; k++) {
        int i = g + k*TT;
        #pragma unroll
        for (int c = 0; c < 3; c++) {
            float d = sWt[c*4+0]*w[k][0] + sWt[c*4+1]*w[k][1]
                    + sWt[c*4+2]*w[k][2] + sWt[c*4+3]*w[k][3];
            float e = expf(-d * sc);
            out[c*N_PIX + i] = fminf(fmaxf(e, 0.f), 1.f);
        }
    }
}

extern "C" void kernel_launch(void* const* d_in, const int* in_sizes, int n_in,
                              void* d_out, int out_size, void* d_ws, size_t ws_size,
                              hipStream_t stream) {
    const float* pic  = (const float*)d_in[0];
    const float* Wt   = (const float*)d_in[1];
    const float* HtRM = (const float*)d_in[2];
    const float* W0   = (const float*)d_in[3];
    const float* H0   = (const float*)d_in[4];
    float* out = (float*)d_out;

    // zero epoch lines + histograms
    hipMemsetAsync(d_ws, 0, WS_BYTES, stream);
    he_norm_kernel<<<dim3(NB), dim3(BS), 0, stream>>>(
        pic, Wt, HtRM, W0, H0, out, (unsigned char*)d_ws);
}